// Round 7
// baseline (63.719 us; speedup 1.0000x reference)
//
#include <hip/hip_runtime.h>
#include <hip/hip_bf16.h>
#include <cstdint>

#define BB 64
#define CC 256
#define EPSF 1e-5f
#define PLANES 4
#define ZROW 24
#define SSTR 65          // snapshot row stride in dwords
#define NPLANES (BB * CC)
#define BDSTR 128        // per-b stride (dwords) in bounds buffer
// bd layout per b (dwords): [0..1] needm, [2..3] snapm, [4..39] pk(36),
// [40..75] cnt(36), [76..77] colm   -- NO overlaps.

// ---------------------------------------------------------------------------
// Bit-exact replication of the reference float32 bound arithmetic for ONE
// (bank, i, j) cell. No FMA contraction (__f*_rn), floorf, int32 truncation.
// bank 0 = subj(bbox_s), 1 = subj(bbox_o), 2 = joint(clip s), 3 = joint(clip o)
// ---------------------------------------------------------------------------
__device__ __forceinline__ void region_bounds(int bank, int i, int j,
                                              float sy0, float sy1, float sx0, float sx1,
                                              float oy0, float oy1, float ox0, float ox1,
                                              int& r0, int& r1, int& c0, int& c1) {
    float fi = (float)i, fj = (float)j;
    if (bank < 2) {
        float y0 = bank ? oy0 : sy0, y1 = bank ? oy1 : sy1;
        float x0 = bank ? ox0 : sx0, x1 = bank ? ox1 : sx1;
        float ch = __fdiv_rn(__fsub_rn(y1, y0), 3.0f);
        float cw = __fdiv_rn(__fsub_rn(x1, x0), 3.0f);
        int R0 = (int)floorf(__fmul_rn(64.0f, __fadd_rn(y0, __fmul_rn(fi, ch))));
        int R1 = (int)floorf(__fmul_rn(64.0f, __fadd_rn(y0, __fmul_rn(__fadd_rn(fi, 1.0f), ch))));
        bool dr = (R1 <= R0);
        r1 = (dr && (R1 < 63)) ? R1 + 1 : R1;
        r0 = (dr && (R1 >= 63)) ? R0 - 1 : R0;
        int C0 = (int)floorf(__fmul_rn(64.0f, __fadd_rn(x0, __fmul_rn(fj, cw))));
        int C1 = (int)floorf(__fmul_rn(64.0f, __fadd_rn(x0, __fmul_rn(__fadd_rn(fj, 1.0f), cw))));
        bool dc = (C1 <= C0);
        c1 = (dc && (C1 < 64)) ? C1 + 1 : C1;
        c0 = (dc && (C1 >= 64)) ? C0 - 1 : C0;
    } else {
        float by0 = (bank == 2) ? sy0 : oy0, by1 = (bank == 2) ? sy1 : oy1;
        float bx0 = (bank == 2) ? sx0 : ox0, bx1 = (bank == 2) ? sx1 : ox1;
        float uy0 = fminf(sy0, oy0), uy1 = fmaxf(sy1, oy1);
        float ux0 = fminf(sx0, ox0), ux1 = fmaxf(sx1, ox1);
        float ch = __fdiv_rn(__fsub_rn(uy1, uy0), 3.0f);
        float cw = __fdiv_rn(__fsub_rn(ux1, ux0), 3.0f);
        float ylo = __fadd_rn(uy0, __fmul_rn(fi, ch));
        float yhi = __fadd_rn(uy0, __fmul_rn(__fadd_rn(fi, 1.0f), ch));
        float xlo = __fadd_rn(ux0, __fmul_rn(fj, cw));
        float xhi = __fadd_rn(ux0, __fmul_rn(__fadd_rn(fj, 1.0f), cw));
        r0 = (int)floorf(__fmul_rn(64.0f, fmaxf(by0, ylo)));
        r1 = (int)floorf(__fmul_rn(64.0f, fminf(by1, yhi)));
        c0 = (int)floorf(__fmul_rn(64.0f, fmaxf(bx0, xlo)));
        c1 = (int)floorf(__fmul_rn(64.0f, fminf(bx1, xhi)));
    }
}

// ---------------------------------------------------------------------------
// Kernel 0: per-b bounds precompute. Grid 64, block 64.
// ---------------------------------------------------------------------------
__global__ __launch_bounds__(64) void k_bounds(const float* __restrict__ bbox_s,
                                               const float* __restrict__ bbox_o,
                                               uint32_t* __restrict__ bd) {
    int b = blockIdx.x, t = threadIdx.x;
    __shared__ unsigned int msk[6];
    if (t < 6) msk[t] = 0u;
    __syncthreads();

    float sy0 = bbox_s[b * 4 + 0], sy1 = bbox_s[b * 4 + 1];
    float sx0 = bbox_s[b * 4 + 2], sx1 = bbox_s[b * 4 + 3];
    float oy0 = bbox_o[b * 4 + 0], oy1 = bbox_o[b * 4 + 1];
    float ox0 = bbox_o[b * 4 + 2], ox1 = bbox_o[b * 4 + 3];

    if (t < 12) {
        int bank = t / 3, idx = t % 3;
        int r0, r1, c0, c1;
        region_bounds(bank, idx, idx, sy0, sy1, sx0, sx1, oy0, oy1, ox0, ox1,
                      r0, r1, c0, c1);
        int r0c = min(max(r0, 0), 64), r1c = min(max(r1, 0), 64);
        if (r1c > r0c) {
            unsigned long long rows =
                ((r1c >= 64) ? ~0ull : ((1ull << r1c) - 1ull)) ^ ((1ull << r0c) - 1ull);
            atomicOr(&msk[0], (unsigned)rows);
            atomicOr(&msk[1], (unsigned)(rows >> 32));
            unsigned long long sn = 1ull << (r1c - 1);
            if (r0c >= 1) sn |= 1ull << (r0c - 1);
            atomicOr(&msk[2], (unsigned)sn);
            atomicOr(&msk[3], (unsigned)(sn >> 32));
        }
        int c0c = min(max(c0, 0), 64), c1c = min(max(c1, 0), 64);
        if (c1c > c0c) {
            unsigned long long cols =
                ((c1c >= 64) ? ~0ull : ((1ull << c1c) - 1ull)) ^ ((1ull << c0c) - 1ull);
            atomicOr(&msk[4], (unsigned)cols);
            atomicOr(&msk[5], (unsigned)(cols >> 32));
        }
    }
    __syncthreads();

    unsigned long long snapm = (((unsigned long long)msk[3]) << 32) | msk[2];
    if (t < 36) {
        int bank = t / 9, ij = t % 9, ii = ij / 3, jj = ij % 3;
        int r0, r1, c0, c1;
        region_bounds(bank, ii, jj, sy0, sy1, sx0, sx1, oy0, oy1, ox0, ox1,
                      r0, r1, c0, c1);
        int r0c = min(max(r0, 0), 64), r1c = min(max(r1, 0), 64);
        int clc = min(max(c0, 0), 64), chc = min(max(c1, 0), 64);
        int nrows = max(0, r1c - r0c), ncols = max(0, chc - clc);
        float cnt = (float)(nrows * ncols);
        int i0 = ZROW, i1 = ZROW;
        if (r1c > r0c) {
            i1 = (int)__popcll(snapm & ((1ull << (r1c - 1)) - 1ull));
            i0 = (r0c > 0) ? (int)__popcll(snapm & ((1ull << (r0c - 1)) - 1ull)) : ZROW;
        }
        bd[b * BDSTR + 4 + t] = (unsigned)clc | ((unsigned)chc << 8) |
                                ((unsigned)i0 << 16) | ((unsigned)i1 << 24);
        bd[b * BDSTR + 40 + t] = __float_as_uint(cnt);
    }
    if (t < 4) bd[b * BDSTR + t] = msk[t];
    if (t == 4 || t == 5) bd[b * BDSTR + 72 + t] = msk[t];  // -> [76],[77]
}

// ---------------------------------------------------------------------------
// Wave64 inclusive scan via DPP (pure VALU, no LDS): row_shr 1/2/4/8 then
// row_bcast:15 (rows 1,3) and row_bcast:31 (rows 2,3).
// ---------------------------------------------------------------------------
__device__ __forceinline__ float dpp_scan_incl(float v) {
    float t;
    t = __int_as_float(__builtin_amdgcn_update_dpp(0, __float_as_int(v), 0x111, 0xf, 0xf, true));  v += t;
    t = __int_as_float(__builtin_amdgcn_update_dpp(0, __float_as_int(v), 0x112, 0xf, 0xf, true));  v += t;
    t = __int_as_float(__builtin_amdgcn_update_dpp(0, __float_as_int(v), 0x114, 0xf, 0xf, true));  v += t;
    t = __int_as_float(__builtin_amdgcn_update_dpp(0, __float_as_int(v), 0x118, 0xf, 0xf, true));  v += t;
    t = __int_as_float(__builtin_amdgcn_update_dpp(0, __float_as_int(v), 0x142, 0xa, 0xf, false)); v += t;
    t = __int_as_float(__builtin_amdgcn_update_dpp(0, __float_as_int(v), 0x143, 0xc, 0xf, false)); v += t;
    return v;
}

// ---------------------------------------------------------------------------
// Kernel 1: column-per-lane streaming. Register column prefix; at each
// snapshot row the wave DPP-scans `run` over columns and stores a summed-area
// row. Region sum = 4 LDS reads (no loop). Rows/cols outside the union are
// never loaded. Loads for plane p+1 are issued before eval of plane p.
// M layout: [plane][36] raw region SUMS.
// ---------------------------------------------------------------------------
__global__ __launch_bounds__(64, 4) void k_region_sums(const float* __restrict__ feat,
                                                       const uint32_t* __restrict__ bd,
                                                       float* __restrict__ M) {
    int l = threadIdx.x;
    int pid0 = blockIdx.x * PLANES;
    int b = pid0 >> 8;

    const uint32_t* bdp = bd + b * BDSTR;
    unsigned long long needm, snapm, colm;
    {
        unsigned int n0 = __builtin_amdgcn_readfirstlane(bdp[0]);
        unsigned int n1 = __builtin_amdgcn_readfirstlane(bdp[1]);
        unsigned int s0 = __builtin_amdgcn_readfirstlane(bdp[2]);
        unsigned int s1 = __builtin_amdgcn_readfirstlane(bdp[3]);
        unsigned int c0 = __builtin_amdgcn_readfirstlane(bdp[76]);
        unsigned int c1 = __builtin_amdgcn_readfirstlane(bdp[77]);
        needm = (((unsigned long long)n1) << 32) | n0;
        snapm = (((unsigned long long)s1) << 32) | s0;
        colm  = (((unsigned long long)c1) << 32) | c0;
    }
    bool colact = ((colm >> l) & 1ull) != 0ull;

    uint32_t pk = bdp[4 + l];  // defined for l<64; only used under l<36 guard
    int cl   = pk & 255;
    int chx  = (pk >> 8) & 255;
    int idx0 = (pk >> 16) & 255;
    int idx1 = (pk >> 24) & 255;

    __shared__ float S[(ZROW + 1) * SSTR];
    if (l < ZROW + 1) S[l * SSTR] = 0.0f;       // col 0 of every slot row
    S[ZROW * SSTR + 1 + l] = 0.0f;              // zero row, cols 1..64
    __syncthreads();

    float xA[32], xB[32];

#define ISSUE(P)                                                            \
    do {                                                                    \
        const float* pp = feat + (size_t)(pid0 + (P)) * 4096 + l;           \
        _Pragma("unroll")                                                   \
        for (int h = 0; h < 32; ++h) {                                      \
            if ((needm >> h) & 1ull) {                                      \
                float v = 0.0f;                                             \
                if (colact) v = pp[h * 64];                                 \
                xA[h] = v;                                                  \
            }                                                               \
        }                                                                   \
        _Pragma("unroll")                                                   \
        for (int h = 0; h < 32; ++h) {                                      \
            if ((needm >> (h + 32)) & 1ull) {                               \
                float v = 0.0f;                                             \
                if (colact) v = pp[(h + 32) * 64];                          \
                xB[h] = v;                                                  \
            }                                                               \
        }                                                                   \
    } while (0)

#define CONSUME()                                                           \
    do {                                                                    \
        float run = 0.0f;                                                   \
        int slot = 0;                                                       \
        _Pragma("unroll")                                                   \
        for (int h = 0; h < 32; ++h) {                                      \
            if ((needm >> h) & 1ull) run += xA[h];                          \
            if ((snapm >> h) & 1ull) {                                      \
                S[slot * SSTR + 1 + l] = dpp_scan_incl(run);                \
                ++slot;                                                     \
            }                                                               \
        }                                                                   \
        _Pragma("unroll")                                                   \
        for (int h = 0; h < 32; ++h) {                                      \
            if ((needm >> (h + 32)) & 1ull) run += xB[h];                   \
            if ((snapm >> (h + 32)) & 1ull) {                               \
                S[slot * SSTR + 1 + l] = dpp_scan_incl(run);                \
                ++slot;                                                     \
            }                                                               \
        }                                                                   \
    } while (0)

#define EVAL(P)                                                             \
    do {                                                                    \
        if (l < 36) {                                                       \
            float s = S[idx1 * SSTR + chx] - S[idx1 * SSTR + cl] -          \
                      S[idx0 * SSTR + chx] + S[idx0 * SSTR + cl];           \
            M[(size_t)(pid0 + (P)) * 36 + l] = s;                           \
        }                                                                   \
    } while (0)

    ISSUE(0);
    #pragma unroll
    for (int p = 0; p < PLANES; ++p) {
        CONSUME();
        if (p == 0) ISSUE(1);
        if (p == 1) ISSUE(2);
        if (p == 2) ISSUE(3);
        __syncthreads();
        EVAL(p);
        __syncthreads();
    }

#undef ISSUE
#undef CONSUME
#undef EVAL
}

// ---------------------------------------------------------------------------
// Kernel 2a: dot. One block per (b, bank) -> 256 blocks. Stage this bank's
// 9 region rows of M[b] transposed (MlT9[ij][c]), 81 threads dot 256
// channels with conv_w (float4), BN2 + precomputed count mask.
// ---------------------------------------------------------------------------
__global__ __launch_bounds__(128) void k_head_dot(const float* __restrict__ M,
                                                  const uint32_t* __restrict__ bd,
                                                  const float* __restrict__ conv_w,
                                                  const float* __restrict__ conv_b,
                                                  const float* __restrict__ g2,
                                                  const float* __restrict__ b2,
                                                  const float* __restrict__ m2,
                                                  const float* __restrict__ v2,
                                                  float* __restrict__ val) {
    int blk = blockIdx.x;
    int b = blk >> 2, bank = blk & 3;
    int t = threadIdx.x;

    __shared__ float MlT9[9 * 264];
    for (int i = t; i < 9 * 256; i += 128) {
        int ij = i >> 8, c = i & 255;
        MlT9[ij * 264 + c] = M[(size_t)(b * 256 + c) * 36 + bank * 9 + ij];
    }
    __syncthreads();

    if (t < 81) {
        int ij = t / 9, k = t - ij * 9;
        int ii = ij / 3, jj = ij % 3;
        int o = bank * 81 + ii * 27 + jj * 9 + k;
        float cnt = __uint_as_float(bd[b * BDSTR + 40 + bank * 9 + ij]);

        float v = 0.0f;
        if (cnt > 0.0f) {
            const float4* wv = (const float4*)(conv_w + o * 256);
            const float4* mv = (const float4*)(&MlT9[ij * 264]);
            float4 a4 = make_float4(0.f, 0.f, 0.f, 0.f);
            #pragma unroll 8
            for (int c4 = 0; c4 < 64; ++c4) {
                float4 wq = wv[c4], mq = mv[c4];
                a4.x += wq.x * mq.x; a4.y += wq.y * mq.y;
                a4.z += wq.z * mq.z; a4.w += wq.w * mq.w;
            }
            float dot = (a4.x + a4.y) + (a4.z + a4.w);
            float mean = dot / cnt;
            float sc = g2[o] / sqrtf(v2[o] + EPSF);
            v = (mean + conv_b[o] - m2[o]) * sc + b2[o];
        }
        val[b * 324 + bank * 81 + t] = v;
    }
}

// ---------------------------------------------------------------------------
// Kernel 2b: fold banks + tiny MLP + predicate dot. One block per b.
// ---------------------------------------------------------------------------
__global__ __launch_bounds__(128) void k_head_mlp(const float* __restrict__ val,
                                                  const float* __restrict__ fc1_w,
                                                  const float* __restrict__ fc1_b,
                                                  const float* __restrict__ g1,
                                                  const float* __restrict__ b1,
                                                  const float* __restrict__ m1,
                                                  const float* __restrict__ v1,
                                                  const float* __restrict__ fc2_w,
                                                  const float* __restrict__ fc2_b,
                                                  const float* __restrict__ pred,
                                                  float* __restrict__ out) {
    int b = blockIdx.x;
    int t = threadIdx.x;

    __shared__ float fv[81];
    __shared__ float hv[40];
    __shared__ float lg[9];

    if (t < 81) {
        int k = t / 9, ij = t - k * 9;
        const float* vb = val + b * 324;
        fv[t] = vb[0 * 81 + ij * 9 + k] + vb[1 * 81 + ij * 9 + k] +
                vb[2 * 81 + ij * 9 + k] + vb[3 * 81 + ij * 9 + k];
    }
    __syncthreads();

    if (t < 40) {
        float h = fc1_b[t];
        for (int u = 0; u < 81; ++u) h += fv[u] * fc1_w[t * 81 + u];
        h = (h - m1[t]) * (g1[t] / sqrtf(v1[t] + EPSF)) + b1[t];
        hv[t] = h;
    }
    __syncthreads();

    if (t < 9) {
        float lgt = fc2_b[t];
        for (int u = 0; u < 40; ++u) lgt += hv[u] * fc2_w[t * 40 + u];
        lg[t] = lgt * pred[b * 9 + t];
    }
    __syncthreads();

    if (t == 0) {
        float s = 0.0f;
        for (int i = 0; i < 9; ++i) s += lg[i];
        out[b] = s;
    }
}

extern "C" void kernel_launch(void* const* d_in, const int* in_sizes, int n_in,
                              void* d_out, int out_size, void* d_ws, size_t ws_size,
                              hipStream_t stream) {
    const float* feat   = (const float*)d_in[0];
    const float* bbox_s = (const float*)d_in[1];
    const float* bbox_o = (const float*)d_in[2];
    const float* pred   = (const float*)d_in[3];
    const float* conv_w = (const float*)d_in[4];
    const float* conv_b = (const float*)d_in[5];
    const float* g2     = (const float*)d_in[6];
    const float* b2     = (const float*)d_in[7];
    const float* m2     = (const float*)d_in[8];
    const float* v2     = (const float*)d_in[9];
    const float* fc1_w  = (const float*)d_in[10];
    const float* fc1_b  = (const float*)d_in[11];
    const float* g1     = (const float*)d_in[12];
    const float* b1     = (const float*)d_in[13];
    const float* m1     = (const float*)d_in[14];
    const float* v1     = (const float*)d_in[15];
    const float* fc2_w  = (const float*)d_in[16];
    const float* fc2_b  = (const float*)d_in[17];
    float* out = (float*)d_out;

    char* ws = (char*)d_ws;
    float*    M   = (float*)ws;                         // 16384*36*4 = 2359296 B
    uint32_t* bdb = (uint32_t*)(ws + 2359296);          // 64*128*4   =   32768 B
    float*    val = (float*)(ws + 2359296 + 32768);     // 64*324*4   =   82944 B

    k_bounds<<<BB, 64, 0, stream>>>(bbox_s, bbox_o, bdb);
    k_region_sums<<<(BB * CC) / PLANES, 64, 0, stream>>>(feat, bdb, M);
    k_head_dot<<<BB * 4, 128, 0, stream>>>(M, bdb, conv_w, conv_b, g2, b2, m2, v2, val);
    k_head_mlp<<<BB, 128, 0, stream>>>(val, fc1_w, fc1_b, g1, b1, m1, v1,
                                       fc2_w, fc2_b, pred, out);
}

// Round 8
// 56.242 us; speedup vs baseline: 1.1329x; 1.1329x over previous
//
#include <hip/hip_runtime.h>
#include <hip/hip_bf16.h>
#include <cstdint>

#define BB 64
#define CC 256
#define EPSF 1e-5f
#define PLANES 4
#define ZROW 24
#define SSTR 65        // snapshot row stride (65 mod 32 = 1 -> conflict-free)
#define NPLANES (BB * CC)

// ---------------------------------------------------------------------------
// Bit-exact replication of the reference float32 bound arithmetic for ONE
// (bank, i, j) cell. No FMA contraction (__f*_rn), floorf, int32 truncation.
// Row bounds depend only on i; col bounds only on j.
// bank 0 = subj(bbox_s), 1 = subj(bbox_o), 2 = joint(clip s), 3 = joint(clip o)
// ---------------------------------------------------------------------------
__device__ __forceinline__ void region_bounds(int bank, int i, int j,
                                              float sy0, float sy1, float sx0, float sx1,
                                              float oy0, float oy1, float ox0, float ox1,
                                              int& r0, int& r1, int& c0, int& c1) {
    float fi = (float)i, fj = (float)j;
    if (bank < 2) {
        float y0 = bank ? oy0 : sy0, y1 = bank ? oy1 : sy1;
        float x0 = bank ? ox0 : sx0, x1 = bank ? ox1 : sx1;
        float ch = __fdiv_rn(__fsub_rn(y1, y0), 3.0f);
        float cw = __fdiv_rn(__fsub_rn(x1, x0), 3.0f);
        int R0 = (int)floorf(__fmul_rn(64.0f, __fadd_rn(y0, __fmul_rn(fi, ch))));
        int R1 = (int)floorf(__fmul_rn(64.0f, __fadd_rn(y0, __fmul_rn(__fadd_rn(fi, 1.0f), ch))));
        bool dr = (R1 <= R0);
        r1 = (dr && (R1 < 63)) ? R1 + 1 : R1;
        r0 = (dr && (R1 >= 63)) ? R0 - 1 : R0;
        int C0 = (int)floorf(__fmul_rn(64.0f, __fadd_rn(x0, __fmul_rn(fj, cw))));
        int C1 = (int)floorf(__fmul_rn(64.0f, __fadd_rn(x0, __fmul_rn(__fadd_rn(fj, 1.0f), cw))));
        bool dc = (C1 <= C0);
        c1 = (dc && (C1 < 64)) ? C1 + 1 : C1;
        c0 = (dc && (C1 >= 64)) ? C0 - 1 : C0;
    } else {
        float by0 = (bank == 2) ? sy0 : oy0, by1 = (bank == 2) ? sy1 : oy1;
        float bx0 = (bank == 2) ? sx0 : ox0, bx1 = (bank == 2) ? sx1 : ox1;
        float uy0 = fminf(sy0, oy0), uy1 = fmaxf(sy1, oy1);
        float ux0 = fminf(sx0, ox0), ux1 = fmaxf(sx1, ox1);
        float ch = __fdiv_rn(__fsub_rn(uy1, uy0), 3.0f);
        float cw = __fdiv_rn(__fsub_rn(ux1, ux0), 3.0f);
        float ylo = __fadd_rn(uy0, __fmul_rn(fi, ch));
        float yhi = __fadd_rn(uy0, __fmul_rn(__fadd_rn(fi, 1.0f), ch));
        float xlo = __fadd_rn(ux0, __fmul_rn(fj, cw));
        float xhi = __fadd_rn(ux0, __fmul_rn(__fadd_rn(fj, 1.0f), cw));
        r0 = (int)floorf(__fmul_rn(64.0f, fmaxf(by0, ylo)));
        r1 = (int)floorf(__fmul_rn(64.0f, fminf(by1, yhi)));
        c0 = (int)floorf(__fmul_rn(64.0f, fmaxf(bx0, xlo)));
        c1 = (int)floorf(__fmul_rn(64.0f, fminf(bx1, xhi)));
    }
}

// ---------------------------------------------------------------------------
// Kernel 1: column-per-lane streaming, register column-prefix, needed-row
// masking (uniform scalar branch per row). Columns outside the col-union are
// CLAMPED to the lowest active column (same cache line, no exec juggling);
// their S columns hold garbage but are never read by eval (region cols are
// inside the union). Gap rows cancel in prefix differences, so skipping them
// is exact. M layout: [region 36][plane 16384] for coalesced head reads.
// ---------------------------------------------------------------------------
__global__ __launch_bounds__(64, 4) void k_region_sums(const float* __restrict__ feat,
                                                       const float* __restrict__ bbox_s,
                                                       const float* __restrict__ bbox_o,
                                                       float* __restrict__ M) {
    int l = threadIdx.x;
    int pid0 = blockIdx.x * PLANES;
    int b = pid0 >> 8;

    float sy0 = bbox_s[b * 4 + 0], sy1 = bbox_s[b * 4 + 1];
    float sx0 = bbox_s[b * 4 + 2], sx1 = bbox_s[b * 4 + 3];
    float oy0 = bbox_o[b * 4 + 0], oy1 = bbox_o[b * 4 + 1];
    float ox0 = bbox_o[b * 4 + 2], ox1 = bbox_o[b * 4 + 3];

    int myb = l / 9, rest = l % 9, myi = rest / 3, myj = rest % 3;

    unsigned long long needm = 0ull, snapm = 0ull;
    int my_r0c = 0, my_r1c = 0, mycl = 0, mych = 0;
    bool colact = false;
    int cmin = 64;
    #pragma unroll
    for (int bk = 0; bk < 4; ++bk) {
        #pragma unroll
        for (int idx = 0; idx < 3; ++idx) {
            int r0, r1, c0, c1;
            region_bounds(bk, idx, idx, sy0, sy1, sx0, sx1, oy0, oy1, ox0, ox1,
                          r0, r1, c0, c1);
            int r0c = max(r0, 0), r1c = min(r1, 64);
            if (r1c > r0c) {
                unsigned long long hi = (r1c >= 64) ? ~0ull : ((1ull << r1c) - 1ull);
                unsigned long long lo = (1ull << r0c) - 1ull;
                needm |= hi ^ lo;
                snapm |= 1ull << (r1c - 1);
                if (r0c >= 1) snapm |= 1ull << (r0c - 1);
            }
            int clc = max(c0, 0), chc = min(c1, 64);
            if (chc > clc) {
                colact = colact || (l >= clc && l < chc);
                cmin = min(cmin, clc);
            }
            if (bk == myb && idx == myi) { my_r0c = r0c; my_r1c = r1c; }
            if (bk == myb && idx == myj) { mycl = max(c0, 0); mych = min(c1, 64); }
        }
    }
    // Force masks into SGPRs -> per-row tests are scalar branches.
    {
        unsigned int a = __builtin_amdgcn_readfirstlane((unsigned int)needm);
        unsigned int bm = __builtin_amdgcn_readfirstlane((unsigned int)(needm >> 32));
        needm = (((unsigned long long)bm) << 32) | a;
        unsigned int c = __builtin_amdgcn_readfirstlane((unsigned int)snapm);
        unsigned int d = __builtin_amdgcn_readfirstlane((unsigned int)(snapm >> 32));
        snapm = (((unsigned long long)d) << 32) | c;
    }
    if (cmin >= 64) cmin = 0;
    int col_tgt = colact ? l : cmin;

    // Per-lane eval parameters (lanes 0..35)
    int cl = 0, chx = 0, idx0 = ZROW, idx1 = ZROW;
    if (l < 36) {
        cl = mycl; chx = mych;
        if (my_r1c <= my_r0c) {
            chx = cl;  // empty row range -> skip loop, s = 0
        } else {
            idx1 = (int)__popcll(snapm & ((1ull << (my_r1c - 1)) - 1ull));
            idx0 = (my_r0c > 0) ? (int)__popcll(snapm & ((1ull << (my_r0c - 1)) - 1ull))
                                : ZROW;
        }
    }

    __shared__ float S[(ZROW + 1) * SSTR];
    S[ZROW * SSTR + l] = 0.0f;  // zero row for "no lower boundary"
    __syncthreads();

    const float* pf = feat + (size_t)pid0 * 4096 + col_tgt;
    for (int p = 0; p < PLANES; ++p) {
        float x[32];
        float run = 0.0f;
        int slot = 0;

        #pragma unroll
        for (int h = 0; h < 32; ++h) {
            if ((needm >> h) & 1ull) x[h] = pf[h * 64];
        }
        #pragma unroll
        for (int h = 0; h < 32; ++h) {
            if ((needm >> h) & 1ull) run += x[h];
            if ((snapm >> h) & 1ull) { S[slot * SSTR + l] = run; ++slot; }
        }
        #pragma unroll
        for (int h = 0; h < 32; ++h) {
            if ((needm >> (h + 32)) & 1ull) x[h] = pf[(h + 32) * 64];
        }
        #pragma unroll
        for (int h = 0; h < 32; ++h) {
            if ((needm >> (h + 32)) & 1ull) run += x[h];
            if ((snapm >> (h + 32)) & 1ull) { S[slot * SSTR + l] = run; ++slot; }
        }
        __syncthreads();

        if (l < 36) {
            float s = 0.0f;
            for (int w = cl; w < chx; ++w)
                s += S[idx1 * SSTR + w] - S[idx0 * SSTR + w];
            M[(size_t)l * NPLANES + pid0 + p] = s;
        }
        __syncthreads();
        pf += 4096;
    }
}

// ---------------------------------------------------------------------------
// Kernel 2: fused head. One block per b (64 blocks, 384 threads).
// Stage M[b] transposed as MlT[36][264] (coalesced over planes from the
// [region][plane] layout); 324 threads each dot 256 channels with conv_w
// (float4), BN2 + inline count mask; fold 4 banks -> f[81]; 81->40->9 MLP;
// predicate dot.
// ---------------------------------------------------------------------------
__global__ __launch_bounds__(384) void k_head(const float* __restrict__ M,
                                              const float* __restrict__ bbox_s,
                                              const float* __restrict__ bbox_o,
                                              const float* __restrict__ conv_w,
                                              const float* __restrict__ conv_b,
                                              const float* __restrict__ g2,
                                              const float* __restrict__ b2,
                                              const float* __restrict__ m2,
                                              const float* __restrict__ v2,
                                              const float* __restrict__ fc1_w,
                                              const float* __restrict__ fc1_b,
                                              const float* __restrict__ g1,
                                              const float* __restrict__ b1,
                                              const float* __restrict__ m1,
                                              const float* __restrict__ v1,
                                              const float* __restrict__ fc2_w,
                                              const float* __restrict__ fc2_b,
                                              const float* __restrict__ pred,
                                              float* __restrict__ out) {
    int b = blockIdx.x;
    int t = threadIdx.x;

    __shared__ float MlT[36 * 264];
    __shared__ float val[324];
    __shared__ float fv[81];
    __shared__ float hv[40];
    __shared__ float lg[9];

    for (int i = t; i < 36 * 256; i += 384) {
        int r = i >> 8, c = i & 255;
        MlT[r * 264 + c] = M[(size_t)r * NPLANES + (b << 8) + c];
    }
    __syncthreads();

    if (t < 324) {
        int region = t / 9, k = t - region * 9;
        int bank = region / 9, ij = region - bank * 9;
        int ii = ij / 3, jj = ij % 3;
        int o = bank * 81 + ii * 27 + jj * 9 + k;

        float sy0 = bbox_s[b * 4 + 0], sy1 = bbox_s[b * 4 + 1];
        float sx0 = bbox_s[b * 4 + 2], sx1 = bbox_s[b * 4 + 3];
        float oy0 = bbox_o[b * 4 + 0], oy1 = bbox_o[b * 4 + 1];
        float ox0 = bbox_o[b * 4 + 2], ox1 = bbox_o[b * 4 + 3];
        int r0, r1, c0, c1;
        region_bounds(bank, ii, jj, sy0, sy1, sx0, sx1, oy0, oy1, ox0, ox1,
                      r0, r1, c0, c1);
        int nrows = max(0, min(r1, 64) - max(r0, 0));
        int ncols = max(0, min(c1, 64) - max(c0, 0));
        float cnt = (float)(nrows * ncols);

        float v = 0.0f;
        if (cnt > 0.0f) {
            const float4* wv = (const float4*)(conv_w + o * 256);
            const float4* mv = (const float4*)(&MlT[region * 264]);
            float4 a4 = make_float4(0.f, 0.f, 0.f, 0.f);
            #pragma unroll 8
            for (int c4 = 0; c4 < 64; ++c4) {
                float4 wq = wv[c4], mq = mv[c4];
                a4.x += wq.x * mq.x; a4.y += wq.y * mq.y;
                a4.z += wq.z * mq.z; a4.w += wq.w * mq.w;
            }
            float dot = (a4.x + a4.y) + (a4.z + a4.w);
            float mean = dot / cnt;
            float sc = g2[o] / sqrtf(v2[o] + EPSF);
            v = (mean + conv_b[o] - m2[o]) * sc + b2[o];
        }
        val[t] = v;  // t == bank*81 + ij*9 + k
    }
    __syncthreads();

    if (t < 81) {
        int k = t / 9, ij = t - k * 9;
        fv[t] = val[0 * 81 + ij * 9 + k] + val[1 * 81 + ij * 9 + k] +
                val[2 * 81 + ij * 9 + k] + val[3 * 81 + ij * 9 + k];
    }
    __syncthreads();

    if (t < 40) {
        float h = fc1_b[t];
        for (int u = 0; u < 81; ++u) h += fv[u] * fc1_w[t * 81 + u];
        h = (h - m1[t]) * (g1[t] / sqrtf(v1[t] + EPSF)) + b1[t];
        hv[t] = h;
    }
    __syncthreads();

    if (t < 9) {
        float lgt = fc2_b[t];
        for (int u = 0; u < 40; ++u) lgt += hv[u] * fc2_w[t * 40 + u];
        lg[t] = lgt * pred[b * 9 + t];
    }
    __syncthreads();

    if (t == 0) {
        float s = 0.0f;
        for (int i = 0; i < 9; ++i) s += lg[i];
        out[b] = s;
    }
}

extern "C" void kernel_launch(void* const* d_in, const int* in_sizes, int n_in,
                              void* d_out, int out_size, void* d_ws, size_t ws_size,
                              hipStream_t stream) {
    const float* feat   = (const float*)d_in[0];
    const float* bbox_s = (const float*)d_in[1];
    const float* bbox_o = (const float*)d_in[2];
    const float* pred   = (const float*)d_in[3];
    const float* conv_w = (const float*)d_in[4];
    const float* conv_b = (const float*)d_in[5];
    const float* g2     = (const float*)d_in[6];
    const float* b2     = (const float*)d_in[7];
    const float* m2     = (const float*)d_in[8];
    const float* v2     = (const float*)d_in[9];
    const float* fc1_w  = (const float*)d_in[10];
    const float* fc1_b  = (const float*)d_in[11];
    const float* g1     = (const float*)d_in[12];
    const float* b1     = (const float*)d_in[13];
    const float* m1     = (const float*)d_in[14];
    const float* v1     = (const float*)d_in[15];
    const float* fc2_w  = (const float*)d_in[16];
    const float* fc2_b  = (const float*)d_in[17];
    float* out = (float*)d_out;

    float* M = (float*)d_ws;  // 36*16384*4 = 2359296 B

    k_region_sums<<<(BB * CC) / PLANES, 64, 0, stream>>>(feat, bbox_s, bbox_o, M);
    k_head<<<BB, 384, 0, stream>>>(M, bbox_s, bbox_o, conv_w, conv_b, g2, b2, m2, v2,
                                   fc1_w, fc1_b, g1, b1, m1, v1, fc2_w, fc2_b,
                                   pred, out);
}